// Round 8
// baseline (39.056 us; speedup 1.0000x reference)
//
#include <hip/hip_runtime.h>
#include <hip/hip_bf16.h>

// Problem constants (hardcoded in the reference)
#define B_SZ 512
#define D_SZ 1024
#define NK 160
#define NCOL 480          // NK*3
#define OUTW 1184         // D + NK
#define LOG2E 1.44269504088896340736f

typedef __attribute__((ext_vector_type(8))) short bf16x8;
typedef __attribute__((ext_vector_type(4))) float f32x4;

__device__ __forceinline__ unsigned int f32_bf16_rne(float f) {
    unsigned int u = __float_as_uint(f);
    u += 0x7fffu + ((u >> 16) & 1u);   // round-to-nearest-even at bf16 boundary
    return u >> 16;
}
__device__ __forceinline__ unsigned int pk2(float x, float y) {
    return f32_bf16_rne(x) | (f32_bf16_rne(y) << 16);
}
__device__ __forceinline__ float bf16u_to_f32(unsigned int h) {
    return __uint_as_float(h << 16);
}

// ---------------- Dispatch 1: input->out copy (blocks 0..511) +
// W transpose/hi-lo-split (blocks 512..751, r4-verified coalesced tile code).
__global__ __launch_bounds__(256) void mbd_prep_kernel(
    const float* __restrict__ A,        // [512][1024]
    const float* __restrict__ W,        // [1024][480]
    unsigned int* __restrict__ Whi_u,   // [480][512] bf16-pairs == Wt[480][1024] bf16
    unsigned int* __restrict__ Wlo_u,   // residual (W - bf16(W)) in bf16
    float* __restrict__ out)            // [512][1184]
{
    __shared__ float lds_t[64][33];     // W tile, padded
    const int b = blockIdx.x, t = threadIdx.x;
    if (b < 512) {
        const float4 v = *reinterpret_cast<const float4*>(&A[b * D_SZ + t * 4]);
        *reinterpret_cast<float4*>(&out[b * OUTW + t * 4]) = v;
        return;
    }
    const int bw = b - 512;          // 0..239
    const int c0 = (bw % 15) * 32;   // col tile
    const int k0 = (bw / 15) * 64;   // k tile
#pragma unroll
    for (int p = 0; p < 8; ++p) {
        const int k = p * 8 + (t >> 5);
        lds_t[k][t & 31] = W[(k0 + k) * NCOL + c0 + (t & 31)];
    }
    __syncthreads();
#pragma unroll
    for (int p = 0; p < 4; ++p) {
        const int flat = p * 256 + t;       // 0..1023
        const int col = flat >> 5;          // 0..31
        const int kkp = flat & 31;          // 0..31
        const float w0 = lds_t[2 * kkp + 0][col];
        const float w1 = lds_t[2 * kkp + 1][col];
        const unsigned int h0 = f32_bf16_rne(w0), h1 = f32_bf16_rne(w1);
        const unsigned int l0 = f32_bf16_rne(w0 - bf16u_to_f32(h0));
        const unsigned int l1 = f32_bf16_rne(w1 - bf16u_to_f32(h1));
        const int idx = (c0 + col) * 512 + (k0 >> 1) + kkp;
        Whi_u[idx] = h0 | (h1 << 16);
        Wlo_u[idx] = l0 | (l1 << 16);
    }
}

// ---------------- Dispatch 2: zero-LDS zero-drain MFMA GEMM.
// 960 blocks x 256 thr; block = 16(M) x 16(N) tile; wave kq handles K-chunk
// kq*256; fragments fed DIRECTLY from global (A: 2xfloat4 + in-reg bf16 pack;
// W: one 16B load each from pre-transposed hi/lo). Only 2 barriers per block
// (split-K combine through 4KB LDS). Frag layout (verified r3-r7):
// A/B lane l -> row/col = l&15, k = (l>>4)*8 + ks*32 + j.
__global__ __launch_bounds__(256) void mbd_gemm_kernel(
    const float* __restrict__ A,              // [512][1024]
    const unsigned int* __restrict__ Whi_u,   // [480][512] pairs
    const unsigned int* __restrict__ Wlo_u,   // [480][512] pairs
    const float* __restrict__ bias,           // [480]
    float* __restrict__ act_t)                // [480][512] f32, pre-scaled by log2e
{
    __shared__ f32x4 comb[4][64];
    // XCD-bijective map: xcd = bid&7 owns bm {4x..4x+3} x all bn -> A L2-local
    const int bid = blockIdx.x;               // 0..959
    const int loc = bid >> 3;                 // 0..119
    const int bm = (bid & 7) * 4 + loc / 30;  // 0..31
    const int bn = loc % 30;                  // 0..29
    const int i0 = bm * 16, c0 = bn * 16;
    const int t = threadIdx.x;
    const int kq = t >> 6;                    // wave 0..3 = K-split
    const int l = t & 63, lhi = l >> 4, llo = l & 15;

    const float* __restrict__ arow = A + (size_t)(i0 + llo) * D_SZ;
    const unsigned int* __restrict__ whp = Whi_u + (size_t)(c0 + llo) * 512;
    const unsigned int* __restrict__ wlp = Wlo_u + (size_t)(c0 + llo) * 512;

    f32x4 acc = {0.f, 0.f, 0.f, 0.f};
    const int kb = kq * 256 + lhi * 8;
#pragma unroll
    for (int ks = 0; ks < 8; ++ks) {
        const int k0 = kb + ks * 32;
        const float4 a0 = *reinterpret_cast<const float4*>(arow + k0);
        const float4 a1 = *reinterpret_cast<const float4*>(arow + k0 + 4);
        uint4 ap;
        ap.x = pk2(a0.x, a0.y); ap.y = pk2(a0.z, a0.w);
        ap.z = pk2(a1.x, a1.y); ap.w = pk2(a1.z, a1.w);
        const bf16x8 af = __builtin_bit_cast(bf16x8, ap);
        const bf16x8 wh = *reinterpret_cast<const bf16x8*>(whp + (k0 >> 1));
        const bf16x8 wl = *reinterpret_cast<const bf16x8*>(wlp + (k0 >> 1));
        acc = __builtin_amdgcn_mfma_f32_16x16x32_bf16(af, wh, acc, 0, 0, 0);
        acc = __builtin_amdgcn_mfma_f32_16x16x32_bf16(af, wl, acc, 0, 0, 0);
    }
    comb[kq][l] = acc;
    __syncthreads();
    if (t < 64) {
        const f32x4 s = comb[0][l] + comb[1][l] + comb[2][l] + comb[3][l];
        const int col = c0 + llo;
        const float bs = bias[col];
        float4 o;   // C/D layout: col = lane&15, row = (lane>>4)*4 + reg
        o.x = (s[0] + bs) * LOG2E;
        o.y = (s[1] + bs) * LOG2E;
        o.z = (s[2] + bs) * LOG2E;
        o.w = (s[3] + bs) * LOG2E;
        *reinterpret_cast<float4*>(&act_t[(size_t)col * B_SZ + i0 + lhi * 4]) = o;
    }
}

// ---------------- Dispatch 3: pairwise (r7-verified, unchanged).
// 2560 blocks x 64 thr; 4 rows/lane, stride-8 j-interleave; 1 ds_read_b128
// feeds 4 rows. acts pre-scaled by log2e so exp(-d)==exp2(-d').
__global__ __launch_bounds__(64) void mbd_pairwise_kernel(
    const float* __restrict__ act_t,   // [480][512] planes
    float* __restrict__ out)           // [512][1184]
{
    __shared__ float4 as4[B_SZ];
    const int bid = blockIdx.x;
    const int klin = (bid & 7) * 320 + (bid >> 3);   // XCD-bijective
    const int k = klin >> 4;           // 0..159
    const int c = klin & 15;           // 0..15 (32-row chunk)
    const int t = threadIdx.x;         // 0..63

    const float* __restrict__ p0 = act_t + (size_t)(3 * k + 0) * B_SZ;
    const float* __restrict__ p1 = act_t + (size_t)(3 * k + 1) * B_SZ;
    const float* __restrict__ p2 = act_t + (size_t)(3 * k + 2) * B_SZ;
#pragma unroll
    for (int s = 0; s < 8; ++s) {
        const int idx = t + s * 64;
        as4[idx] = make_float4(p0[idx], p1[idx], p2[idx], 0.f);
    }
    __syncthreads();

    const int jq = t >> 3;             // 0..7 j-slice
    const int rg = t & 7;              // 0..7 row group
    const int r0 = c * 32 + rg * 4;
    const float4 a0 = as4[r0 + 0];
    const float4 a1 = as4[r0 + 1];
    const float4 a2 = as4[r0 + 2];
    const float4 a3 = as4[r0 + 3];

    float acc0 = 0.f, acc1 = 0.f, acc2 = 0.f, acc3 = 0.f;
#pragma unroll 8
    for (int jj = 0; jj < 64; ++jj) {
        const float4 av = as4[jq + jj * 8];
        acc0 += __builtin_amdgcn_exp2f(-(fabsf(a0.x - av.x) + fabsf(a0.y - av.y) + fabsf(a0.z - av.z)));
        acc1 += __builtin_amdgcn_exp2f(-(fabsf(a1.x - av.x) + fabsf(a1.y - av.y) + fabsf(a1.z - av.z)));
        acc2 += __builtin_amdgcn_exp2f(-(fabsf(a2.x - av.x) + fabsf(a2.y - av.y) + fabsf(a2.z - av.z)));
        acc3 += __builtin_amdgcn_exp2f(-(fabsf(a3.x - av.x) + fabsf(a3.y - av.y) + fabsf(a3.z - av.z)));
    }
#pragma unroll
    for (int m = 8; m <= 32; m <<= 1) {
        acc0 += __shfl_xor(acc0, m);
        acc1 += __shfl_xor(acc1, m);
        acc2 += __shfl_xor(acc2, m);
        acc3 += __shfl_xor(acc3, m);
    }
    if (t < 8) {
        out[(size_t)(r0 + 0) * OUTW + D_SZ + k] = acc0;
        out[(size_t)(r0 + 1) * OUTW + D_SZ + k] = acc1;
        out[(size_t)(r0 + 2) * OUTW + D_SZ + k] = acc2;
        out[(size_t)(r0 + 3) * OUTW + D_SZ + k] = acc3;
    }
}

extern "C" void kernel_launch(void* const* d_in, const int* in_sizes, int n_in,
                              void* d_out, int out_size, void* d_ws, size_t ws_size,
                              hipStream_t stream)
{
    const float* inputs = (const float*)d_in[0];   // [512,1024] f32
    const float* W      = (const float*)d_in[1];   // [1024,480] f32
    const float* bias   = (const float*)d_in[2];   // [480] f32
    float* out = (float*)d_out;                    // [512,1184] f32

    char* ws = (char*)d_ws;
    unsigned int* Whi_u = (unsigned int*)(ws);                 // 983,040 B
    unsigned int* Wlo_u = (unsigned int*)(ws + 983040);        // 983,040 B
    float*        act_t = (float*)      (ws + 2 * 983040);     // 983,040 B

    mbd_prep_kernel<<<752, 256, 0, stream>>>(inputs, W, Whi_u, Wlo_u, out);
    mbd_gemm_kernel<<<960, 256, 0, stream>>>(inputs, Whi_u, Wlo_u, bias, act_t);
    mbd_pairwise_kernel<<<NK * 16, 64, 0, stream>>>(act_t, out);
}

// Round 10
// 30.307 us; speedup vs baseline: 1.2887x; 1.2887x over previous
//
#include <hip/hip_runtime.h>
#include <hip/hip_bf16.h>

// Problem constants (hardcoded in the reference)
#define B_SZ 512
#define D_SZ 1024
#define NK 160
#define NCOL 480          // NK*3
#define OUTW 1184         // D + NK
#define LOG2E 1.44269504088896340736f

typedef __attribute__((ext_vector_type(8))) short bf16x8;
typedef __attribute__((ext_vector_type(4))) float f32x4;

__device__ __forceinline__ unsigned int f32_bf16_rne(float f) {
    unsigned int u = __float_as_uint(f);
    u += 0x7fffu + ((u >> 16) & 1u);   // round-to-nearest-even at bf16 boundary
    return u >> 16;
}
__device__ __forceinline__ unsigned int pk2(float x, float y) {
    return f32_bf16_rne(x) | (f32_bf16_rne(y) << 16);
}

// ---------------- Node 1: pure GEMM, W cast to bf16 on the fly (no residual).
// 480 blocks x 256 thr; tile 32(M) x 16(N); K-chunk 256 (4 chunks), dbuf 48KB LDS.
// 4 waves K-split within chunk: wave w -> ks {2w,2w+1}; LDS-combine epilogue.
// act_t[col][i] = (A[i,:].W[:,col] + b[col]) * log2e.
__global__ __launch_bounds__(256) void mbd_gemm_kernel(
    const float* __restrict__ A,      // [512][1024]
    const float* __restrict__ W,      // [1024][480]
    const float* __restrict__ bias,   // [480]
    float* __restrict__ act_t)        // ws: [480][512] f32, pre-scaled by log2e
{
    __shared__ char lds[49152];       // 2 bufs x (A 32x512B=16K @0 + W 16x512B=8K @16384)
    const int bid = blockIdx.x;       // 0..479
    const int loc = bid >> 3;         // 0..59
    const int bm = (bid & 7) * 2 + (loc & 1);   // 0..15 (XCD-local A rows)
    const int bn = loc >> 1;                    // 0..29
    const int i0 = bm * 32, c0 = bn * 16;
    const int t = threadIdx.x;
    const int w = __builtin_amdgcn_readfirstlane(t >> 6);  // 0..3 uniform
    const int l = t & 63, lhi = l >> 4, llo = l & 15;

    // staging roles: A: row 0..31 x 64B-seg 0..7 (32 f32/thread, contiguous);
    // W: col 0..15 x k-group 0..15 (16 strided f32/thread; 16 cols = full 64B line).
    const int arow = t >> 3, aseg = t & 7;
    const int wcol = t & 15, wkg = t >> 4;
    const int aswz = (arow & 7) << 4;
    const int wswz = (wcol & 7) << 4;
    const float* __restrict__ aptr = A + (size_t)(i0 + arow) * D_SZ + aseg * 32;
    const float* __restrict__ wptr = W + (size_t)wkg * 16 * NCOL + c0 + wcol;

    float4 ra[8];
    float rw[16];
    f32x4 acc0 = {0.f, 0.f, 0.f, 0.f}, acc1 = {0.f, 0.f, 0.f, 0.f};

    auto issue_loads = [&](int k0) {
#pragma unroll
        for (int q = 0; q < 8; ++q)
            ra[q] = *reinterpret_cast<const float4*>(aptr + k0 + q * 4);
#pragma unroll
        for (int j = 0; j < 16; ++j)
            rw[j] = wptr[(size_t)(k0 + j) * NCOL];
    };
    auto write_stage = [&](int buf) {
        char* base = lds + buf * 24576;
        // A: 32 f32 -> 16 bf16-pairs = 4 uint4; seg aseg owns bytes [aseg*64, aseg*64+64)
        // (r9 BUG was aseg*128: overflowed the 512B row -> garbage fragments)
        char* arp = base + arow * 512;
#pragma unroll
        for (int q = 0; q < 4; ++q) {
            uint4 p;
            p.x = pk2(ra[2 * q].x, ra[2 * q].y);
            p.y = pk2(ra[2 * q].z, ra[2 * q].w);
            p.z = pk2(ra[2 * q + 1].x, ra[2 * q + 1].y);
            p.w = pk2(ra[2 * q + 1].z, ra[2 * q + 1].w);
            *reinterpret_cast<uint4*>(arp + ((aseg * 64 + q * 16) ^ aswz)) = p;
        }
        // W: 16 f32 -> 8 pairs = 2 uint4 at col wcol, k-bytes wkg*32..+32, swizzled
        char* wrp = base + 16384 + wcol * 512;
        uint4 p0, p1;
        p0.x = pk2(rw[0], rw[1]);  p0.y = pk2(rw[2], rw[3]);
        p0.z = pk2(rw[4], rw[5]);  p0.w = pk2(rw[6], rw[7]);
        p1.x = pk2(rw[8], rw[9]);  p1.y = pk2(rw[10], rw[11]);
        p1.z = pk2(rw[12], rw[13]); p1.w = pk2(rw[14], rw[15]);
        *reinterpret_cast<uint4*>(wrp + ((wkg * 32) ^ wswz)) = p0;
        *reinterpret_cast<uint4*>(wrp + ((wkg * 32 + 16) ^ wswz)) = p1;
    };
    auto compute = [&](int buf) {
        const char* base = lds + buf * 24576;
        const int rswz = (llo & 7) << 4;
#pragma unroll
        for (int ks2 = 0; ks2 < 2; ++ks2) {
            const int kb = (lhi * 16 + (2 * w + ks2) * 64) ^ rswz;
            const bf16x8 af0 = *reinterpret_cast<const bf16x8*>(base + llo * 512 + kb);
            const bf16x8 af1 = *reinterpret_cast<const bf16x8*>(base + (16 + llo) * 512 + kb);
            const bf16x8 bf  = *reinterpret_cast<const bf16x8*>(base + 16384 + llo * 512 + kb);
            acc0 = __builtin_amdgcn_mfma_f32_16x16x32_bf16(af0, bf, acc0, 0, 0, 0);
            acc1 = __builtin_amdgcn_mfma_f32_16x16x32_bf16(af1, bf, acc1, 0, 0, 0);
        }
    };

    issue_loads(0);
    write_stage(0);
    __syncthreads();
    for (int ch = 0; ch < 4; ++ch) {
        if (ch < 3) issue_loads((ch + 1) * 256);   // in flight during MFMA
        compute(ch & 1);
        if (ch < 3) {
            __syncthreads();
            write_stage((ch + 1) & 1);
            __syncthreads();
        }
    }
    __syncthreads();
    // K-split combine: comb[w*2+tile][lane] in buf0 region (last compute used buf1)
    f32x4* comb = reinterpret_cast<f32x4*>(lds);
    comb[(w * 2 + 0) * 64 + l] = acc0;
    comb[(w * 2 + 1) * 64 + l] = acc1;
    __syncthreads();
    if (t < 128) {
        const int th = t >> 6;                 // row tile 0/1
        const int l2 = t & 63, llo2 = l2 & 15, lhi2 = l2 >> 4;
        f32x4 s = comb[(0 + th) * 64 + l2] + comb[(2 + th) * 64 + l2]
                + comb[(4 + th) * 64 + l2] + comb[(6 + th) * 64 + l2];
        const int col = c0 + llo2;
        const float bs = bias[col];
        float4 o;   // C/D layout: col = lane&15, row = (lane>>4)*4 + reg
        o.x = (s[0] + bs) * LOG2E;
        o.y = (s[1] + bs) * LOG2E;
        o.z = (s[2] + bs) * LOG2E;
        o.w = (s[3] + bs) * LOG2E;
        *reinterpret_cast<float4*>(&act_t[(size_t)col * B_SZ + i0 + th * 16 + lhi2 * 4]) = o;
    }
}

// ---------------- Node 2: pairwise (r7-verified) + input->out copy (bid<512).
// 2560 blocks x 64 thr; 4 rows/lane, stride-8 j-interleave; 1 ds_read_b128
// feeds 4 rows. acts pre-scaled by log2e so exp(-d)==exp2(-d').
__global__ __launch_bounds__(64) void mbd_pairwise_kernel(
    const float* __restrict__ A,       // [512][1024] (for the copy)
    const float* __restrict__ act_t,   // [480][512] planes
    float* __restrict__ out)           // [512][1184]
{
    __shared__ float4 as4[B_SZ];
    const int bid = blockIdx.x;
    const int t = threadIdx.x;         // 0..63

    // fused input copy: first 512 blocks each copy one row (64 thr x 4 float4)
    if (bid < 512) {
#pragma unroll
        for (int s = 0; s < 4; ++s) {
            const int idx = t + s * 64;
            const float4 v = *reinterpret_cast<const float4*>(&A[bid * D_SZ + idx * 4]);
            *reinterpret_cast<float4*>(&out[bid * OUTW + idx * 4]) = v;
        }
    }

    const int klin = (bid & 7) * 320 + (bid >> 3);   // XCD-bijective
    const int k = klin >> 4;           // 0..159
    const int c = klin & 15;           // 0..15 (32-row chunk)

    const float* __restrict__ p0 = act_t + (size_t)(3 * k + 0) * B_SZ;
    const float* __restrict__ p1 = act_t + (size_t)(3 * k + 1) * B_SZ;
    const float* __restrict__ p2 = act_t + (size_t)(3 * k + 2) * B_SZ;
#pragma unroll
    for (int s = 0; s < 8; ++s) {
        const int idx = t + s * 64;
        as4[idx] = make_float4(p0[idx], p1[idx], p2[idx], 0.f);
    }
    __syncthreads();

    const int jq = t >> 3;             // 0..7 j-slice
    const int rg = t & 7;              // 0..7 row group
    const int r0 = c * 32 + rg * 4;
    const float4 a0 = as4[r0 + 0];
    const float4 a1 = as4[r0 + 1];
    const float4 a2 = as4[r0 + 2];
    const float4 a3 = as4[r0 + 3];

    float acc0 = 0.f, acc1 = 0.f, acc2 = 0.f, acc3 = 0.f;
#pragma unroll 8
    for (int jj = 0; jj < 64; ++jj) {
        const float4 av = as4[jq + jj * 8];
        acc0 += __builtin_amdgcn_exp2f(-(fabsf(a0.x - av.x) + fabsf(a0.y - av.y) + fabsf(a0.z - av.z)));
        acc1 += __builtin_amdgcn_exp2f(-(fabsf(a1.x - av.x) + fabsf(a1.y - av.y) + fabsf(a1.z - av.z)));
        acc2 += __builtin_amdgcn_exp2f(-(fabsf(a2.x - av.x) + fabsf(a2.y - av.y) + fabsf(a2.z - av.z)));
        acc3 += __builtin_amdgcn_exp2f(-(fabsf(a3.x - av.x) + fabsf(a3.y - av.y) + fabsf(a3.z - av.z)));
    }
#pragma unroll
    for (int m = 8; m <= 32; m <<= 1) {
        acc0 += __shfl_xor(acc0, m);
        acc1 += __shfl_xor(acc1, m);
        acc2 += __shfl_xor(acc2, m);
        acc3 += __shfl_xor(acc3, m);
    }
    if (t < 8) {
        out[(size_t)(r0 + 0) * OUTW + D_SZ + k] = acc0;
        out[(size_t)(r0 + 1) * OUTW + D_SZ + k] = acc1;
        out[(size_t)(r0 + 2) * OUTW + D_SZ + k] = acc2;
        out[(size_t)(r0 + 3) * OUTW + D_SZ + k] = acc3;
    }
}

extern "C" void kernel_launch(void* const* d_in, const int* in_sizes, int n_in,
                              void* d_out, int out_size, void* d_ws, size_t ws_size,
                              hipStream_t stream)
{
    const float* inputs = (const float*)d_in[0];   // [512,1024] f32
    const float* W      = (const float*)d_in[1];   // [1024,480] f32
    const float* bias   = (const float*)d_in[2];   // [480] f32
    float* out = (float*)d_out;                    // [512,1184] f32
    float* act_t = (float*)d_ws;                   // [480][512] f32 = 983,040 B

    mbd_gemm_kernel<<<480, 256, 0, stream>>>(inputs, W, bias, act_t);
    mbd_pairwise_kernel<<<NK * 16, 64, 0, stream>>>(inputs, act_t, out);
}